// Round 6
// baseline (547.858 us; speedup 1.0000x reference)
//
#include <hip/hip_runtime.h>
#include <hip/hip_bf16.h>

// ---------------------------------------------------------------------------
// MPS contraction, N=512 sites, D_PHY=4, D_BOND=128, VOC=1024.
// Faithful computation with EXACT all-zero early exit (state underflows to
// exact 0 after ~15 sites; site map is linear, so remaining sites stay 0).
// Round-6: 1024-thread wgs (4 waves/SIMD, halved phase lengths -> less
// latency exposure and less max-of-128 skew); QR reduction rounds fused
// (20 -> 11 sync rounds); Ms back to a tiny global table with per-site
// REGISTER prefetch of the next site's 4 M values (kills a cold IF$ read
// on the C-step critical path). Warming, flat barrier, bypass S exchange
// and transposed S layout unchanged from round 5.
// ---------------------------------------------------------------------------

__device__ __forceinline__ float2 cfma(float2 a, float2 b, float2 acc) {
    acc.x = fmaf(a.x, b.x, fmaf(-a.y, b.y, acc.x));
    acc.y = fmaf(a.x, b.y, fmaf( a.y, b.x, acc.y));
    return acc;
}
__device__ __forceinline__ float2 cfmac(float2 a, float2 b, float2 acc) {
    // acc + conj(a)*b
    acc.x = fmaf(a.x, b.x, fmaf( a.y, b.y, acc.x));
    acc.y = fmaf(a.x, b.y, fmaf(-a.y, b.x, acc.y));
    return acc;
}

// coherent (cache-bypassing) 8-byte load/store for the S exchange
__device__ __forceinline__ float2 ld_coh(const float2* p) {
    union { unsigned long long u; float2 f; } cv;
    cv.u = __hip_atomic_load((const unsigned long long*)p,
                             __ATOMIC_RELAXED, __HIP_MEMORY_SCOPE_AGENT);
    return cv.f;
}
__device__ __forceinline__ void st_coh(float2* p, float2 x) {
    union { unsigned long long u; float2 f; } cv;
    cv.f = x;
    __hip_atomic_store((unsigned long long*)p, cv.u,
                       __ATOMIC_RELAXED, __HIP_MEMORY_SCOPE_AGENT);
}

__device__ __forceinline__ double2 d2mul(double2 a, double2 b) {
    return make_double2(a.x*b.x - a.y*b.y, a.x*b.y + a.y*b.x);
}
__device__ __forceinline__ double2 d2conj(double2 a) { return make_double2(a.x, -a.y); }

// batched block reduction over 512 threads (8 waves): reduces n (<=4)
// double2 values in ONE sync round. Deterministic.
__device__ void qr_redN(double2* v, int n, double2 (*redm)[4]) {
    for (int off = 32; off; off >>= 1) {
        for (int d = 0; d < n; ++d) {
            v[d].x += __shfl_down(v[d].x, off, 64);
            v[d].y += __shfl_down(v[d].y, off, 64);
        }
    }
    const int wid = threadIdx.x >> 6, lane = threadIdx.x & 63;
    __syncthreads();
    if (lane == 0)
        for (int d = 0; d < n; ++d) redm[wid][d] = v[d];
    __syncthreads();
    for (int d = 0; d < n; ++d) {
        double2 s = make_double2(0.0, 0.0);
        for (int w = 0; w < 8; ++w) { s.x += redm[w][d].x; s.y += redm[w][d].y; }
        v[d] = s;
    }
}

// ---------------------------------------------------------------------------
// Kernel 1: Householder QR of A (4096 x 4 complex), LAPACK clarfg/cungqr
// convention (beta real, sign rule pins the column phases M depends on).
// Fused multi-column dot reductions: 11 sync rounds instead of 20.
// Also zeroes the 512 barrier words (fresh every replay).
// ---------------------------------------------------------------------------
__global__ __launch_bounds__(512) void qr_kernel(const float* __restrict__ a_re,
                                                 const float* __restrict__ a_im,
                                                 float2* __restrict__ Q,
                                                 unsigned int* __restrict__ cnt)
{
    const int t = threadIdx.x;
    cnt[t] = 0u;

    __shared__ double2 redm[8][4];
    __shared__ double2 bc;

    float2 a[8][4];
    for (int i = 0; i < 8; ++i) {
        int r = t + 512 * i;
        for (int j = 0; j < 4; ++j)
            a[i][j] = make_float2(a_re[r*4 + j], a_im[r*4 + j]);
    }
    double2 tau[4];

    for (int k = 0; k < 4; ++k) {
        if (t == k) bc = make_double2((double)a[0][k].x, (double)a[0][k].y);
        __syncthreads();
        const double ar = bc.x, ai = bc.y;

        double xn = 0.0;
        for (int i = 0; i < 8; ++i) {
            int r = t + 512 * i;
            if (r > k) xn += (double)a[i][k].x * a[i][k].x + (double)a[i][k].y * a[i][k].y;
        }
        double2 vv[4];
        vv[0] = make_double2(xn, 0.0);
        qr_redN(vv, 1, redm);
        xn = vv[0].x;

        double2 tk, scale;
        if (xn == 0.0 && ai == 0.0) {
            tk = make_double2(0.0, 0.0);
            scale = make_double2(0.0, 0.0);
        } else {
            double nrm = sqrt(ar*ar + ai*ai + xn);
            double beta = (ar >= 0.0) ? -nrm : nrm;       // clarfg sign rule
            tk = make_double2((beta - ar) / beta, -ai / beta);
            double dr = ar - beta, di = ai;
            double dd = dr*dr + di*di;
            scale = make_double2(dr / dd, -di / dd);      // 1/(alpha-beta)
        }
        tau[k] = tk;

        for (int i = 0; i < 8; ++i) {
            int r = t + 512 * i;
            if (r == k) a[i][k] = make_float2(1.f, 0.f);
            else if (r > k) {
                double2 v = d2mul(make_double2(a[i][k].x, a[i][k].y), scale);
                a[i][k] = make_float2((float)v.x, (float)v.y);
            } else a[i][k] = make_float2(0.f, 0.f);
        }
        __syncthreads();

        const int nd = 3 - k;
        if (nd > 0) {
            // fused dots: w[jj] = v^H A[:, k+1+jj]
            for (int jj = 0; jj < nd; ++jj) {
                double2 w = make_double2(0.0, 0.0);
                const int j = k + 1 + jj;
                for (int i = 0; i < 8; ++i) {
                    double2 vvk = make_double2(a[i][k].x, a[i][k].y);
                    double2 aa  = make_double2(a[i][j].x, a[i][j].y);
                    double2 m = d2mul(d2conj(vvk), aa);
                    w.x += m.x; w.y += m.y;
                }
                vv[jj] = w;
            }
            qr_redN(vv, nd, redm);
            for (int jj = 0; jj < nd; ++jj) {
                const int j = k + 1 + jj;
                double2 cw = d2mul(d2conj(tk), vv[jj]);
                for (int i = 0; i < 8; ++i) {
                    double2 vvk = make_double2(a[i][k].x, a[i][k].y);
                    double2 upd = d2mul(cw, vvk);
                    a[i][j] = make_float2((float)((double)a[i][j].x - upd.x),
                                          (float)((double)a[i][j].y - upd.y));
                }
            }
        }
    }

    // cungqr: Q = H1..H4 * I; one fused round per k
    float2 q[8][4];
    for (int i = 0; i < 8; ++i) {
        int r = t + 512 * i;
        for (int j = 0; j < 4; ++j)
            q[i][j] = make_float2((r == j) ? 1.f : 0.f, 0.f);
    }
    for (int k = 3; k >= 0; --k) {
        const int nd = 4 - k;
        double2 vv[4];
        for (int jj = 0; jj < nd; ++jj) {
            const int j = k + jj;
            double2 w = make_double2(0.0, 0.0);
            for (int i = 0; i < 8; ++i) {
                double2 vvk = make_double2(a[i][k].x, a[i][k].y);
                double2 qq  = make_double2(q[i][j].x, q[i][j].y);
                double2 m = d2mul(d2conj(vvk), qq);
                w.x += m.x; w.y += m.y;
            }
            vv[jj] = w;
        }
        qr_redN(vv, nd, redm);
        for (int jj = 0; jj < nd; ++jj) {
            const int j = k + jj;
            double2 cw = d2mul(tau[k], vv[jj]);
            for (int i = 0; i < 8; ++i) {
                double2 vvk = make_double2(a[i][k].x, a[i][k].y);
                double2 upd = d2mul(cw, vvk);
                q[i][j] = make_float2((float)((double)q[i][j].x - upd.x),
                                      (float)((double)q[i][j].y - upd.y));
            }
        }
    }
    for (int i = 0; i < 8; ++i) {
        int r = t + 512 * i;
        for (int j = 0; j < 4; ++j) Q[r*4 + j] = q[i][j];
    }
}

// ---------------------------------------------------------------------------
// Kernel 2: Ms[t][j][k] = sum_i conj(Q[4v+i,j]) Q[4v+i,k], v=tokens[t].
// ---------------------------------------------------------------------------
__global__ __launch_bounds__(256) void ms_kernel(const float2* __restrict__ Q,
                                                 const int* __restrict__ tokens,
                                                 float2* __restrict__ Ms)
{
    const int idx = blockIdx.x * 256 + threadIdx.x;   // 32 blocks -> 8192
    if (idx < 8192) {
        const int ti = idx >> 4, jk = idx & 15, j = jk >> 2, kk = jk & 3;
        const int v = tokens[ti];
        float2 s = make_float2(0.f, 0.f);
        for (int i = 0; i < 4; ++i) {
            float2 q1 = Q[(v*4 + i)*4 + j];
            float2 q2 = Q[(v*4 + i)*4 + kk];
            s.x += q1.x*q2.x + q1.y*q2.y;     // conj(q1)*q2
            s.y += q1.x*q2.y - q1.y*q2.x;
        }
        Ms[idx] = s;
    }
}

// ---------------------------------------------------------------------------
// Flat fused grid barrier + liveness, fence-free (round-3 design).
// S stores are write-through (sc0+sc1); __syncthreads() drains vmcnt for
// every wave, so by the time tid 0 adds, this wg's S is globally visible.
// Count field == 128 => word final => liveness bits consistent & uniform.
// ---------------------------------------------------------------------------
#define NWG 128u
__device__ __forceinline__ bool site_barrier(unsigned int* addr,
                                             unsigned* nzw, int* live_lds, int tid)
{
    __syncthreads();                 // drains vmcnt(0) for all waves
    if (tid == 0) {
        unsigned add = 1u | ((nzw[0] | nzw[1]) ? 0x10000u : 0u);
        __hip_atomic_fetch_add(addr, add, __ATOMIC_RELAXED, __HIP_MEMORY_SCOPE_AGENT);
        unsigned v;
        for (;;) {
            v = __hip_atomic_load(addr, __ATOMIC_RELAXED, __HIP_MEMORY_SCOPE_AGENT);
            if ((v & 0xffffu) >= NWG) break;
            __builtin_amdgcn_s_sleep(1);
        }
        *live_lds = (int)(v >> 16);
    }
    __syncthreads();
    return *live_lds != 0;
}

// ---------------------------------------------------------------------------
// Kernel 3: site 0 + cooperative scan t=1..510 + final site.
// 128 wgs x 1024 threads (4 waves/SIMD); wg owns output column c.
// Per site: C[p][b] = sum_q M[p,q] B[q,b,c]     (prefetched regs -> LDS)
//           U[p][a] = sum_b S[a,b] C[p][b]       (eighth-split b)
//           S'[r,c] = sum_pa conj(B[p,a,r]) U[pa](eighth-split pa)
// Plus cooperative L3-warming of tile t (used at t+1) each iteration,
// and register prefetch of next site's Ms row + C-step B values.
// ---------------------------------------------------------------------------
__global__ __launch_bounds__(1024) void scan_kernel(
    const float* __restrict__ bm_re, const float* __restrict__ bm_im,
    const float* __restrict__ b0_re, const float* __restrict__ b0_im,
    const float* __restrict__ bl_re, const float* __restrict__ bl_im,
    const float2* __restrict__ Ms,
    float2* SbufA, float2* SbufB,
    unsigned int* cnt, float* out, int out_size)
{
    const int tid = threadIdx.x;
    const int bid = blockIdx.x;
    const int c = ((bid & 7) << 4) | (bid >> 3);   // same-XCD wgs -> adjacent c

    __shared__ float2 Clds[4][128];
    __shared__ float2 Upart[8][512];
    __shared__ float2 U[512];
    __shared__ float2 red8[8][128];
    __shared__ float2 fred[16];
    __shared__ unsigned nzw[2];
    __shared__ int live_lds;

    const int a = tid & 127;
    const int o = tid >> 7;          // eighth id 0..7 (2 waves per eighth)

    float2* Sread = SbufA;
    float2* Swrite = SbufB;
    bool dead = false;
    float warmacc = 0.f;

    // ---- warm tile 0 (used by out-step at t=1)
    {
        const int g = (c << 9) | (tid & 511);
        warmacc += (o < 4) ? bm_re[g] : bm_im[g];
    }

    // ---- site 0: threads tid<128 compute column c of S0 (transposed store)
    if (tid < 128) {
        const int r = a;
        float2 brr[4], bcc[4];
        for (int p = 0; p < 4; ++p) {
            brr[p] = make_float2(b0_re[p*128 + r], b0_im[p*128 + r]);
            bcc[p] = make_float2(b0_re[p*128 + c], b0_im[p*128 + c]);
        }
        float2 acc = make_float2(0.f, 0.f);
        for (int p = 0; p < 4; ++p) {
            float2 tp = make_float2(0.f, 0.f);
            for (int q = 0; q < 4; ++q) tp = cfma(Ms[p*4 + q], bcc[q], tp);
            acc = cfmac(brr[p], tp, acc);
        }
        st_coh(&SbufA[c*128 + r], acc);
        int nz = (acc.x != 0.f) || (acc.y != 0.f);
        unsigned long long m = __ballot(nz);
        if ((tid & 63) == 0) nzw[tid >> 6] = (m != 0ULL) ? 1u : 0u;
    }

    // ---- prefetch C-step B values + Ms row for site t=1 (threads o<4)
    float prr[4], pri[4];
    float2 mt[4];
    if (o < 4) {
        for (int q = 0; q < 4; ++q) {
            prr[q] = bm_re[(q*128 + a)*128 + c];
            pri[q] = bm_im[(q*128 + a)*128 + c];
            mt[q]  = Ms[16 + o*4 + q];
        }
    }

    if (!site_barrier(&cnt[0], nzw, &live_lds, tid)) dead = true;

    if (!dead) {
        for (int t = 1; t <= 510; ++t) {
            const float* br = bm_re + (size_t)(t - 1) * 65536;
            const float* bi = bm_im + (size_t)(t - 1) * 65536;

            // ---- issue warm load for tile t (used by out-step at t+1)
            float w0 = 0.f;
            if (t < 510) {
                const int g = (c << 9) | (tid & 511);
                w0 = (o < 4) ? (bm_re + (size_t)t * 65536)[g]
                             : (bm_im + (size_t)t * 65536)[g];
            }

            // ---- C[p][b] from prefetched regs (thread: p=o, b=a; o<4)
            if (o < 4) {
                float2 acc = make_float2(0.f, 0.f);
                for (int q = 0; q < 4; ++q)
                    acc = cfma(mt[q], make_float2(prr[q], pri[q]), acc);
                Clds[o][a] = acc;
            }
            __syncthreads();

            // ---- issue prefetch for next site (drains at the site barrier)
            float prr_n[4], pri_n[4];
            float2 mt_n[4];
            if (o < 4) {
                if (t < 510) {
                    const float* brn = bm_re + (size_t)t * 65536;
                    const float* bin = bm_im + (size_t)t * 65536;
                    for (int q = 0; q < 4; ++q) {
                        prr_n[q] = brn[(q*128 + a)*128 + c];
                        pri_n[q] = bin[(q*128 + a)*128 + c];
                        mt_n[q]  = Ms[(t + 1)*16 + o*4 + q];
                    }
                } else {
                    for (int q = 0; q < 4; ++q) {
                        prr_n[q] = 0.f; pri_n[q] = 0.f;
                        mt_n[q] = make_float2(0.f, 0.f);
                    }
                }
            }

            // ---- U[p][a] = sum_b S[a,b] C[p][b]; eighth-split b
            float2 u0 = make_float2(0,0), u1 = u0, u2 = u0, u3 = u0;
            #pragma unroll
            for (int bb = o * 16; bb < o * 16 + 16; ++bb) {
                float2 s = ld_coh(&Sread[bb * 128 + a]);   // bypass, coalesced
                u0 = cfma(s, Clds[0][bb], u0);
                u1 = cfma(s, Clds[1][bb], u1);
                u2 = cfma(s, Clds[2][bb], u2);
                u3 = cfma(s, Clds[3][bb], u3);
            }
            Upart[o][0*128 + a] = u0;
            Upart[o][1*128 + a] = u1;
            Upart[o][2*128 + a] = u2;
            Upart[o][3*128 + a] = u3;
            __syncthreads();
            if (tid < 512) {
                float2 s = make_float2(0,0);
                #pragma unroll
                for (int w = 0; w < 8; ++w) {
                    float2 x = Upart[w][tid];
                    s.x += x.x; s.y += x.y;
                }
                U[tid] = s;
            }
            __syncthreads();

            // ---- S'[r,c] partial: eighth-split pa (tile is L2/L3-warm)
            const int r = a;
            float2 o0 = make_float2(0,0), o1 = o0;
            #pragma unroll 8
            for (int pa = o * 64; pa < o * 64 + 64; pa += 2) {
                float2 b1 = make_float2(br[pa*128 + r],     bi[pa*128 + r]);
                float2 b2 = make_float2(br[(pa+1)*128 + r], bi[(pa+1)*128 + r]);
                o0 = cfmac(b1, U[pa],     o0);
                o1 = cfmac(b2, U[pa + 1], o1);
            }
            o0.x += o1.x; o0.y += o1.y;
            red8[o][r] = o0;
            __syncthreads();
            if (tid < 128) {
                float2 fin = make_float2(0,0);
                #pragma unroll
                for (int w = 0; w < 8; ++w) {
                    float2 x = red8[w][r];
                    fin.x += x.x; fin.y += x.y;
                }
                st_coh(&Swrite[c * 128 + r], fin);          // write-through
                int nz = (fin.x != 0.f) || (fin.y != 0.f);
                unsigned long long m = __ballot(nz);
                if ((tid & 63) == 0) nzw[tid >> 6] = (m != 0ULL) ? 1u : 0u;
            }
            warmacc += w0;                    // keep warm loads live

            if (!site_barrier(&cnt[t], nzw, &live_lds, tid)) { dead = true; break; }
            float2* tmp = Sread; Sread = Swrite; Swrite = tmp;
            if (o < 4) {
                for (int q = 0; q < 4; ++q) {
                    prr[q] = prr_n[q]; pri[q] = pri_n[q]; mt[q] = mt_n[q];
                }
            }
        }
    }

    if (out_size < 0) out[2] = warmacc;        // never true: keeps warm loads

    if (dead) {
        if (bid == 0 && tid == 0) {
            out[0] = 0.f;
            if (out_size > 1) out[1] = 0.f;
        }
        return;
    }
    if (bid != 0) return;

    // ---- final site: Bl (4,128,1), Ms[511]; Sread holds S(510) transposed
    const float2* Mt = Ms + 511 * 16;
    if (o < 4) {   // t1[q=o][a] = sum_b S[a,b] * Bl[q,b]
        float2 acc = make_float2(0,0);
        for (int b = 0; b < 128; ++b) {
            float2 s = ld_coh(&Sread[b * 128 + a]);
            float2 bl = make_float2(bl_re[o*128 + b], bl_im[o*128 + b]);
            acc = cfma(s, bl, acc);
        }
        Clds[o][a] = acc;
    }
    __syncthreads();
    float2 tot = make_float2(0,0);
    if (o < 4) {
        float2 tp = make_float2(0,0);
        for (int q = 0; q < 4; ++q) tp = cfma(Mt[o*4 + q], Clds[q][a], tp);
        float2 blv = make_float2(bl_re[o*128 + a], bl_im[o*128 + a]);
        tot = cfmac(blv, tp, make_float2(0,0));
    }
    for (int off = 32; off; off >>= 1) {
        tot.x += __shfl_down(tot.x, off, 64);
        tot.y += __shfl_down(tot.y, off, 64);
    }
    if ((tid & 63) == 0) fred[tid >> 6] = tot;
    __syncthreads();
    if (tid == 0) {
        float2 s = make_float2(0,0);
        for (int w = 0; w < 16; ++w) { s.x += fred[w].x; s.y += fred[w].y; }
        out[0] = s.x;
        if (out_size > 1) out[1] = s.y;
    }
}

// ---------------------------------------------------------------------------
extern "C" void kernel_launch(void* const* d_in, const int* in_sizes, int n_in,
                              void* d_out, int out_size, void* d_ws, size_t ws_size,
                              hipStream_t stream)
{
    const float* a_re  = (const float*)d_in[0];
    const float* a_im  = (const float*)d_in[1];
    const float* b0_re = (const float*)d_in[2];
    const float* b0_im = (const float*)d_in[3];
    const float* bm_re = (const float*)d_in[4];
    const float* bm_im = (const float*)d_in[5];
    const float* bl_re = (const float*)d_in[6];
    const float* bl_im = (const float*)d_in[7];
    const int*  tokens = (const int*)d_in[8];

    char* ws = (char*)d_ws;
    float2* Q    = (float2*)(ws);                     // 131072 B
    float2* Ms   = (float2*)(ws + 131072);            //  65536 B
    float2* S0   = (float2*)(ws + 196608);            // 131072 B
    float2* S1b  = (float2*)(ws + 327680);            // 131072 B
    unsigned int* cnt = (unsigned int*)(ws + 458752); // 2048 B

    qr_kernel<<<dim3(1), dim3(512), 0, stream>>>(a_re, a_im, Q, cnt);
    ms_kernel<<<dim3(32), dim3(256), 0, stream>>>((const float2*)Q, tokens, Ms);

    float* outf = (float*)d_out;
    int osz = out_size;
    void* args[] = {
        (void*)&bm_re, (void*)&bm_im, (void*)&b0_re, (void*)&b0_im,
        (void*)&bl_re, (void*)&bl_im,
        (void*)&Ms, (void*)&S0, (void*)&S1b, (void*)&cnt, (void*)&outf, (void*)&osz
    };
    hipLaunchCooperativeKernel((const void*)scan_kernel, dim3(128), dim3(1024),
                               args, 0, stream);
}

// Round 7
// 260.344 us; speedup vs baseline: 2.1044x; 2.1044x over previous
//
#include <hip/hip_runtime.h>
#include <hip/hip_bf16.h>

// ---------------------------------------------------------------------------
// MPS contraction, N=512 sites, D_PHY=4, D_BOND=128, VOC=1024.
// Faithful computation with EXACT all-zero early exit (state underflows to
// exact 0 after ~15 sites; site map is linear, so remaining sites stay 0).
// Round-7:
//  * revert to 512-thr wgs (r6's 1024-thr hit the 64-VGPR cap -> scratch
//    spills -> 340 MB HBM writes; counters showed it unambiguously).
//  * QR/ms kernels DELETED: M_v = (A_v W)^H (A_v W) with W = R^-1 D from
//    in-kernel Gram + Cholesky + LAPACK-sign recurrence (Householder on the
//    Gram/top-rows state). Per-site M computed one site ahead by 16 spare
//    lanes into a double-buffered LDS slot (no extra syncs).
//  * U-step S-loads batched: 16 x global_load_dwordx2 sc0 sc1 + s_waitcnt
//    in ONE asm block (relaxed-atomic loads were serialized by the compiler).
//  * prefetch/warm loads moved after the U-step (exact vmcnt(0)).
// ---------------------------------------------------------------------------

__device__ __forceinline__ float2 cfma(float2 a, float2 b, float2 acc) {
    acc.x = fmaf(a.x, b.x, fmaf(-a.y, b.y, acc.x));
    acc.y = fmaf(a.x, b.y, fmaf( a.y, b.x, acc.y));
    return acc;
}
__device__ __forceinline__ float2 cfmac(float2 a, float2 b, float2 acc) {
    // acc + conj(a)*b
    acc.x = fmaf(a.x, b.x, fmaf( a.y, b.y, acc.x));
    acc.y = fmaf(a.x, b.y, fmaf(-a.y, b.x, acc.y));
    return acc;
}

// coherent (cache-bypassing) 8-byte load/store for the S exchange
__device__ __forceinline__ float2 ld_coh(const float2* p) {
    union { unsigned long long u; float2 f; } cv;
    cv.u = __hip_atomic_load((const unsigned long long*)p,
                             __ATOMIC_RELAXED, __HIP_MEMORY_SCOPE_AGENT);
    return cv.f;
}
__device__ __forceinline__ void st_coh(float2* p, float2 x) {
    union { unsigned long long u; float2 f; } cv;
    cv.f = x;
    __hip_atomic_store((unsigned long long*)p, cv.u,
                       __ATOMIC_RELAXED, __HIP_MEMORY_SCOPE_AGENT);
}

__device__ __forceinline__ double2 d2mul(double2 a, double2 b) {
    return make_double2(a.x*b.x - a.y*b.y, a.x*b.y + a.y*b.x);
}
__device__ __forceinline__ double2 d2conj(double2 a) { return make_double2(a.x, -a.y); }
__device__ __forceinline__ double2 d2add(double2 a, double2 b) {
    return make_double2(a.x + b.x, a.y + b.y);
}
__device__ __forceinline__ double2 d2sub(double2 a, double2 b) {
    return make_double2(a.x - b.x, a.y - b.y);
}

// batched block reduction over 512 threads (8 waves): n (<=4) double2 values
// in one sync round. Deterministic (fixed order).
__device__ void redN(double2* v, int n, double2 (*redm)[4]) {
    for (int off = 32; off; off >>= 1) {
        for (int d = 0; d < n; ++d) {
            v[d].x += __shfl_down(v[d].x, off, 64);
            v[d].y += __shfl_down(v[d].y, off, 64);
        }
    }
    const int wid = threadIdx.x >> 6, lane = threadIdx.x & 63;
    __syncthreads();
    if (lane == 0)
        for (int d = 0; d < n; ++d) redm[wid][d] = v[d];
    __syncthreads();
    for (int d = 0; d < n; ++d) {
        double2 s = make_double2(0.0, 0.0);
        for (int w = 0; w < 8; ++w) { s.x += redm[w][d].x; s.y += redm[w][d].y; }
        v[d] = s;
    }
}

// M entry m=(j,k) for token v: Y = A_v * W (4x4), M[j,k] = sum_i conj(Y[i,j])Y[i,k]
__device__ __forceinline__ float2 m_entry(const float* __restrict__ a_re,
                                          const float* __restrict__ a_im,
                                          int v, int m, const float2* Wl)
{
    const int j = m >> 2, k = m & 3;
    float2 Arow[4][4];
    #pragma unroll
    for (int i = 0; i < 4; ++i) {
        float4 re = *(const float4*)(a_re + v*16 + i*4);
        float4 im = *(const float4*)(a_im + v*16 + i*4);
        Arow[i][0] = make_float2(re.x, im.x);
        Arow[i][1] = make_float2(re.y, im.y);
        Arow[i][2] = make_float2(re.z, im.z);
        Arow[i][3] = make_float2(re.w, im.w);
    }
    float2 acc = make_float2(0.f, 0.f);
    #pragma unroll
    for (int i = 0; i < 4; ++i) {
        float2 yj = make_float2(0.f, 0.f), yk = yj;
        #pragma unroll
        for (int q = 0; q < 4; ++q) {
            yj = cfma(Arow[i][q], Wl[q*4 + j], yj);
            yk = cfma(Arow[i][q], Wl[q*4 + k], yk);
        }
        acc = cfmac(yj, yk, acc);
    }
    return acc;
}

// 16 batched cache-bypassing S loads (one asm block: issue all, wait once)
// t[jj] = Sread[(BB0+jj)*128 + a], consecutive bb stride = 1024 B.
#define LD16_FMA(BB0)                                                         \
  {                                                                           \
    const float2* _p0 = Sread + (BB0) * 128 + a;                              \
    const float2* _p1 = _p0 + 512;                                            \
    const float2* _p2 = _p0 + 1024;                                           \
    const float2* _p3 = _p0 + 1536;                                           \
    float2 t0,t1,t2,t3,t4,t5,t6,t7,t8,t9,t10,t11,t12,t13,t14,t15;             \
    asm volatile(                                                             \
      "global_load_dwordx2 %0, %16, off sc0 sc1\n\t"                          \
      "global_load_dwordx2 %1, %16, off offset:1024 sc0 sc1\n\t"              \
      "global_load_dwordx2 %2, %16, off offset:2048 sc0 sc1\n\t"              \
      "global_load_dwordx2 %3, %16, off offset:3072 sc0 sc1\n\t"              \
      "global_load_dwordx2 %4, %17, off sc0 sc1\n\t"                          \
      "global_load_dwordx2 %5, %17, off offset:1024 sc0 sc1\n\t"              \
      "global_load_dwordx2 %6, %17, off offset:2048 sc0 sc1\n\t"              \
      "global_load_dwordx2 %7, %17, off offset:3072 sc0 sc1\n\t"              \
      "global_load_dwordx2 %8, %18, off sc0 sc1\n\t"                          \
      "global_load_dwordx2 %9, %18, off offset:1024 sc0 sc1\n\t"              \
      "global_load_dwordx2 %10, %18, off offset:2048 sc0 sc1\n\t"             \
      "global_load_dwordx2 %11, %18, off offset:3072 sc0 sc1\n\t"             \
      "global_load_dwordx2 %12, %19, off sc0 sc1\n\t"                         \
      "global_load_dwordx2 %13, %19, off offset:1024 sc0 sc1\n\t"             \
      "global_load_dwordx2 %14, %19, off offset:2048 sc0 sc1\n\t"             \
      "global_load_dwordx2 %15, %19, off offset:3072 sc0 sc1\n\t"             \
      "s_waitcnt vmcnt(0)"                                                    \
      : "=&v"(t0), "=&v"(t1), "=&v"(t2), "=&v"(t3),                           \
        "=&v"(t4), "=&v"(t5), "=&v"(t6), "=&v"(t7),                           \
        "=&v"(t8), "=&v"(t9), "=&v"(t10), "=&v"(t11),                         \
        "=&v"(t12), "=&v"(t13), "=&v"(t14), "=&v"(t15)                        \
      : "v"(_p0), "v"(_p1), "v"(_p2), "v"(_p3));                              \
    float2 tt[16] = {t0,t1,t2,t3,t4,t5,t6,t7,t8,t9,t10,t11,t12,t13,t14,t15};  \
    _Pragma("unroll")                                                         \
    for (int jj = 0; jj < 16; ++jj) {                                         \
        float2 sv = tt[jj];                                                   \
        u0 = cfma(sv, Clds[0][(BB0) + jj], u0);                               \
        u1 = cfma(sv, Clds[1][(BB0) + jj], u1);                               \
        u2 = cfma(sv, Clds[2][(BB0) + jj], u2);                               \
        u3 = cfma(sv, Clds[3][(BB0) + jj], u3);                               \
    }                                                                         \
  }

// ---------------------------------------------------------------------------
// Tiny init: zero the 512 barrier words (fresh every replay).
// ---------------------------------------------------------------------------
__global__ __launch_bounds__(512) void zero_cnt(unsigned int* __restrict__ cnt)
{
    cnt[threadIdx.x] = 0u;
}

// ---------------------------------------------------------------------------
// Flat fused grid barrier + liveness, fence-free (round-3 design).
// S stores are write-through (sc0+sc1); __syncthreads() drains vmcnt for
// every wave, so by the time tid 0 adds, this wg's S is globally visible.
// Count field == 128 => word final => liveness bits consistent & uniform.
// ---------------------------------------------------------------------------
#define NWG 128u
__device__ __forceinline__ bool site_barrier(unsigned int* addr,
                                             unsigned* nzw, int* live_lds, int tid)
{
    __syncthreads();                 // drains vmcnt(0) for all waves
    if (tid == 0) {
        unsigned add = 1u | ((nzw[0] | nzw[1]) ? 0x10000u : 0u);
        __hip_atomic_fetch_add(addr, add, __ATOMIC_RELAXED, __HIP_MEMORY_SCOPE_AGENT);
        unsigned v;
        for (;;) {
            v = __hip_atomic_load(addr, __ATOMIC_RELAXED, __HIP_MEMORY_SCOPE_AGENT);
            if ((v & 0xffffu) >= NWG) break;
            __builtin_amdgcn_s_sleep(1);
        }
        *live_lds = (int)(v >> 16);
    }
    __syncthreads();
    return *live_lds != 0;
}

// ---------------------------------------------------------------------------
// The one cooperative kernel: Gram/Cholesky/D prologue + site 0 + scan + final.
// 128 wgs x 512 threads; wg owns output column c (XCD-grouped mapping).
// ---------------------------------------------------------------------------
__global__ __launch_bounds__(512) void scan_kernel(
    const float* __restrict__ a_re,  const float* __restrict__ a_im,
    const float* __restrict__ b0_re, const float* __restrict__ b0_im,
    const float* __restrict__ bm_re, const float* __restrict__ bm_im,
    const float* __restrict__ bl_re, const float* __restrict__ bl_im,
    const int*  __restrict__ tokens,
    float2* SbufA, float2* SbufB,
    unsigned int* cnt, float* out, int out_size)
{
    const int tid = threadIdx.x;
    const int bid = blockIdx.x;
    const int c = ((bid & 7) << 4) | (bid >> 3);   // same-XCD wgs -> adjacent c

    __shared__ float2 Clds[4][128];
    __shared__ float2 Upart[4][512];
    __shared__ float2 U[512];
    __shared__ float2 red4[4][128];
    __shared__ float2 fred[8];
    __shared__ double2 redm[8][4];
    __shared__ float2 Wlds[16];
    __shared__ float2 MtLds[2][16];
    __shared__ unsigned nzw[2];
    __shared__ int live_lds;

    const int a = tid & 127;
    const int h = tid >> 7;          // quarter id 0..3 (2 waves per quarter)

    float2* Sread = SbufA;
    float2* Swrite = SbufB;
    bool dead = false;
    float warmacc = 0.f;

    // ---- warm tile 0 (used by out-step at t=1)
    {
        const int g  = (c << 9) | tid;
        const int g2 = (g + 32768) & 65535;
        warmacc += bm_re[g] + bm_im[g] + bm_re[g2] + bm_im[g2];
    }

    // =======================================================================
    // Prologue A: Gram G = A^H A (4096x4), every wg redundant & deterministic.
    // =======================================================================
    double2 gp[10];   // upper pairs (0,0)(0,1)(0,2)(0,3)(1,1)(1,2)(1,3)(2,2)(2,3)(3,3)
    #pragma unroll
    for (int e = 0; e < 10; ++e) gp[e] = make_double2(0.0, 0.0);
    for (int rr = 0; rr < 8; ++rr) {
        const int r = tid * 8 + rr;
        float4 fre = *(const float4*)(a_re + r*4);
        float4 fim = *(const float4*)(a_im + r*4);
        double r0 = fre.x, r1 = fre.y, r2 = fre.z, r3 = fre.w;
        double i0 = fim.x, i1 = fim.y, i2 = fim.z, i3 = fim.w;
#define GACC(e, rj, ij, rk, ik) \
        gp[e].x += rj*rk + ij*ik; gp[e].y += rj*ik - ij*rk;
        GACC(0, r0, i0, r0, i0)  GACC(1, r0, i0, r1, i1)
        GACC(2, r0, i0, r2, i2)  GACC(3, r0, i0, r3, i3)
        GACC(4, r1, i1, r1, i1)  GACC(5, r1, i1, r2, i2)
        GACC(6, r1, i1, r3, i3)  GACC(7, r2, i2, r2, i2)
        GACC(8, r2, i2, r3, i3)  GACC(9, r3, i3, r3, i3)
#undef GACC
    }
    redN(gp + 0, 4, redm);
    redN(gp + 4, 4, redm);
    redN(gp + 8, 2, redm);

    double2 G4[4][4];
    G4[0][0]=gp[0]; G4[0][1]=gp[1]; G4[0][2]=gp[2]; G4[0][3]=gp[3];
    G4[1][1]=gp[4]; G4[1][2]=gp[5]; G4[1][3]=gp[6];
    G4[2][2]=gp[7]; G4[2][3]=gp[8]; G4[3][3]=gp[9];
    G4[1][0]=d2conj(gp[1]); G4[2][0]=d2conj(gp[2]); G4[3][0]=d2conj(gp[3]);
    G4[2][1]=d2conj(gp[5]); G4[3][1]=d2conj(gp[6]); G4[3][2]=d2conj(gp[8]);
    G4[0][0].y=0.0; G4[1][1].y=0.0; G4[2][2].y=0.0; G4[3][3].y=0.0;

    // =======================================================================
    // Prologue B: LAPACK diag-sign recurrence (Householder on G + top rows),
    // Cholesky G = R^H R, X = R^-1 (upper), W = X * diag(d). All threads
    // compute redundantly (uniform); tid 0 publishes W.
    // =======================================================================
    {
        double2 T[4][4];
        #pragma unroll
        for (int i = 0; i < 4; ++i)
            #pragma unroll
            for (int j = 0; j < 4; ++j)
                T[i][j] = make_double2((double)a_re[i*4+j], (double)a_im[i*4+j]);

        double dsgn[4];
        #pragma unroll
        for (int k = 0; k < 4; ++k) {
            double ssum = 0.0;
            #pragma unroll
            for (int i = 0; i < 4; ++i)
                if (i <= k) ssum += T[i][k].x*T[i][k].x + T[i][k].y*T[i][k].y;
            double xn = G4[k][k].x - ssum; if (xn < 0.0) xn = 0.0;
            double ar = T[k][k].x, ai = T[k][k].y;
            double nrm = sqrt(ar*ar + ai*ai + xn);
            double beta = (ar >= 0.0) ? -nrm : nrm;        // clarfg sign rule
            dsgn[k] = (beta >= 0.0) ? 1.0 : -1.0;
            double2 tau = make_double2((beta - ar)/beta, -ai/beta);
            double dr = ar - beta, di = ai;
            double dd = dr*dr + di*di;
            double2 s = make_double2(dr/dd, -di/dd);       // 1/(alpha-beta)
            double2 w[4];
            #pragma unroll
            for (int j = 0; j < 4; ++j) if (j > k) {
                double2 acc = G4[k][j];
                #pragma unroll
                for (int i = 0; i < 4; ++i)
                    if (i <= k) acc = d2sub(acc, d2mul(d2conj(T[i][k]), T[i][j]));
                w[j] = d2add(T[k][j], d2mul(d2conj(s), acc));
            }
            #pragma unroll
            for (int j = 0; j < 4; ++j) if (j > k) {
                double2 tw = d2mul(tau, w[j]);
                T[k][j] = d2sub(T[k][j], tw);
                #pragma unroll
                for (int i = 0; i < 4; ++i)
                    if (i > k) T[i][j] = d2sub(T[i][j], d2mul(tw, d2mul(s, T[i][k])));
            }
            T[k][k] = make_double2(beta, 0.0);
            #pragma unroll
            for (int i = 0; i < 4; ++i)
                if (i > k) T[i][k] = make_double2(0.0, 0.0);
        }

        // Cholesky (upper R)
        double2 R[4][4];
        #pragma unroll
        for (int k = 0; k < 4; ++k) {
            double dk = G4[k][k].x;
            #pragma unroll
            for (int i = 0; i < 4; ++i)
                if (i < k) dk -= R[i][k].x*R[i][k].x + R[i][k].y*R[i][k].y;
            if (dk < 1e-30) dk = 1e-30;
            double rkk = sqrt(dk);
            R[k][k] = make_double2(rkk, 0.0);
            #pragma unroll
            for (int j = 0; j < 4; ++j) if (j > k) {
                double2 acc = G4[k][j];
                #pragma unroll
                for (int i = 0; i < 4; ++i)
                    if (i < k) acc = d2sub(acc, d2mul(d2conj(R[i][k]), R[i][j]));
                R[k][j] = make_double2(acc.x/rkk, acc.y/rkk);
            }
        }
        // X = R^-1 (upper triangular back-substitution)
        double2 X[4][4];
        #pragma unroll
        for (int j = 0; j < 4; ++j) {
            #pragma unroll
            for (int i = 0; i < 4; ++i) X[i][j] = make_double2(0.0, 0.0);
            X[j][j] = make_double2(1.0 / R[j][j].x, 0.0);
            #pragma unroll
            for (int ii = 0; ii < 3; ++ii) {
                const int i = j - 1 - ii;
                if (i >= 0) {
                    double2 acc = make_double2(0.0, 0.0);
                    #pragma unroll
                    for (int m2 = 0; m2 < 4; ++m2)
                        if (m2 > i && m2 <= j) acc = d2add(acc, d2mul(R[i][m2], X[m2][j]));
                    X[i][j] = make_double2(-acc.x / R[i][i].x, -acc.y / R[i][i].x);
                }
            }
        }
        if (tid == 0) {
            #pragma unroll
            for (int q = 0; q < 4; ++q)
                #pragma unroll
                for (int j = 0; j < 4; ++j)
                    Wlds[q*4 + j] = make_float2((float)(X[q][j].x * dsgn[j]),
                                                (float)(X[q][j].y * dsgn[j]));
        }
    }
    __syncthreads();

    // ---- M_0 and M_1 (tokens[0], tokens[1]) into the double-buffer
    if (tid < 32) {
        const int which = tid >> 4, m = tid & 15;
        const int v = tokens[which];
        MtLds[which][m] = m_entry(a_re, a_im, v, m, Wlds);
    }
    __syncthreads();

    // ---- site 0: threads tid<128 compute column c of S0 (transposed store)
    if (tid < 128) {
        const int r = a;
        float2 brr[4], bcc[4];
        for (int p = 0; p < 4; ++p) {
            brr[p] = make_float2(b0_re[p*128 + r], b0_im[p*128 + r]);
            bcc[p] = make_float2(b0_re[p*128 + c], b0_im[p*128 + c]);
        }
        float2 acc = make_float2(0.f, 0.f);
        for (int p = 0; p < 4; ++p) {
            float2 tp = make_float2(0.f, 0.f);
            for (int q = 0; q < 4; ++q) tp = cfma(MtLds[0][p*4 + q], bcc[q], tp);
            acc = cfmac(brr[p], tp, acc);
        }
        st_coh(&SbufA[c*128 + r], acc);
        int nz = (acc.x != 0.f) || (acc.y != 0.f);
        unsigned long long m = __ballot(nz);
        if ((tid & 63) == 0) nzw[tid >> 6] = (m != 0ULL) ? 1u : 0u;
    }

    // ---- prefetch C-step B values for site t=1
    float prr[4], pri[4];
    for (int q = 0; q < 4; ++q) {
        prr[q] = bm_re[(q*128 + a)*128 + c];
        pri[q] = bm_im[(q*128 + a)*128 + c];
    }

    if (!site_barrier(&cnt[0], nzw, &live_lds, tid)) dead = true;

    if (!dead) {
        for (int t = 1; t <= 510; ++t) {
            const int cur = t & 1;
            const float* br = bm_re + (size_t)(t - 1) * 65536;
            const float* bi = bm_im + (size_t)(t - 1) * 65536;

            // ---- C[p=h][b=a] from prefetched regs + LDS M row
            {
                float2 acc = make_float2(0.f, 0.f);
                #pragma unroll
                for (int q = 0; q < 4; ++q)
                    acc = cfma(MtLds[cur][h*4 + q], make_float2(prr[q], pri[q]), acc);
                Clds[h][a] = acc;
            }
            __syncthreads();

            // ---- U[p][a] = sum_b S[a,b] C[p][b]; quarter-split b, asm-batched
            float2 u0 = make_float2(0,0), u1 = u0, u2 = u0, u3 = u0;
            LD16_FMA(h * 32)
            LD16_FMA(h * 32 + 16)
            Upart[h][0*128 + a] = u0;
            Upart[h][1*128 + a] = u1;
            Upart[h][2*128 + a] = u2;
            Upart[h][3*128 + a] = u3;
            __syncthreads();
            {
                float2 x0 = Upart[0][tid], x1 = Upart[1][tid];
                float2 x2 = Upart[2][tid], x3 = Upart[3][tid];
                U[tid] = make_float2(x0.x + x1.x + x2.x + x3.x,
                                     x0.y + x1.y + x2.y + x3.y);
            }
            __syncthreads();

            // ---- issue prefetches (drain under out-step + barrier)
            float prr_n[4], pri_n[4];
            float w0 = 0.f, w1 = 0.f, w2 = 0.f, w3 = 0.f;
            if (t < 510) {
                const float* brn = bm_re + (size_t)t * 65536;
                const float* bin = bm_im + (size_t)t * 65536;
                #pragma unroll
                for (int q = 0; q < 4; ++q) {
                    prr_n[q] = brn[(q*128 + a)*128 + c];
                    pri_n[q] = bin[(q*128 + a)*128 + c];
                }
                const int g  = (c << 9) | tid;
                const int g2 = (g + 32768) & 65535;
                w0 = brn[g]; w1 = bin[g]; w2 = brn[g2]; w3 = bin[g2];
            } else {
                #pragma unroll
                for (int q = 0; q < 4; ++q) { prr_n[q] = 0.f; pri_n[q] = 0.f; }
            }
            float2 ArowP[4][4];
            if (tid >= 496) {                       // M_{t+1} operand loads
                const int v1 = tokens[t + 1];
                #pragma unroll
                for (int i = 0; i < 4; ++i) {
                    float4 re = *(const float4*)(a_re + v1*16 + i*4);
                    float4 im = *(const float4*)(a_im + v1*16 + i*4);
                    ArowP[i][0] = make_float2(re.x, im.x);
                    ArowP[i][1] = make_float2(re.y, im.y);
                    ArowP[i][2] = make_float2(re.z, im.z);
                    ArowP[i][3] = make_float2(re.w, im.w);
                }
            }

            // ---- S'[r,c] partial: quarter-split pa (tile is L2/L3-warm)
            const int r = a;
            float2 o0 = make_float2(0,0), o1 = o0;
            #pragma unroll 4
            for (int pa = h * 128; pa < h * 128 + 128; pa += 2) {
                float2 b1 = make_float2(br[pa*128 + r],     bi[pa*128 + r]);
                float2 b2 = make_float2(br[(pa+1)*128 + r], bi[(pa+1)*128 + r]);
                o0 = cfmac(b1, U[pa],     o0);
                o1 = cfmac(b2, U[pa + 1], o1);
            }
            o0.x += o1.x; o0.y += o1.y;
            red4[h][r] = o0;
            __syncthreads();
            if (h == 0) {
                float2 fin = make_float2(
                    red4[0][r].x + red4[1][r].x + red4[2][r].x + red4[3][r].x,
                    red4[0][r].y + red4[1][r].y + red4[2][r].y + red4[3][r].y);
                st_coh(&Swrite[c * 128 + r], fin);          // write-through
                int nz = (fin.x != 0.f) || (fin.y != 0.f);
                unsigned long long m = __ballot(nz);
                if ((tid & 63) == 0) nzw[tid >> 6] = (m != 0ULL) ? 1u : 0u;
            }
            if (tid >= 496) {                       // M_{t+1} -> other buffer
                const int m = tid - 496, j = m >> 2, k = m & 3;
                float2 acc = make_float2(0.f, 0.f);
                #pragma unroll
                for (int i = 0; i < 4; ++i) {
                    float2 yj = make_float2(0.f, 0.f), yk = yj;
                    #pragma unroll
                    for (int q = 0; q < 4; ++q) {
                        yj = cfma(ArowP[i][q], Wlds[q*4 + j], yj);
                        yk = cfma(ArowP[i][q], Wlds[q*4 + k], yk);
                    }
                    acc = cfmac(yj, yk, acc);
                }
                MtLds[cur ^ 1][m] = acc;
            }
            warmacc += w0 + w1 + w2 + w3;           // keep warm loads live

            if (!site_barrier(&cnt[t], nzw, &live_lds, tid)) { dead = true; break; }
            float2* tmp = Sread; Sread = Swrite; Swrite = tmp;
            #pragma unroll
            for (int q = 0; q < 4; ++q) { prr[q] = prr_n[q]; pri[q] = pri_n[q]; }
        }
    }

    if (out_size < 0) out[2] = warmacc;        // never true: keeps warm loads

    if (dead) {
        if (bid == 0 && tid == 0) {
            out[0] = 0.f;
            if (out_size > 1) out[1] = 0.f;
        }
        return;
    }
    if (bid != 0) return;

    // ---- final site: Bl (4,128,1), M_511 = MtLds[1]; Sread = S(510) transposed
    {   // t1[q=h][a] = sum_b S[a,b] * Bl[q,b]
        float2 acc = make_float2(0,0);
        for (int b = 0; b < 128; ++b) {
            float2 s = ld_coh(&Sread[b * 128 + a]);
            float2 bl = make_float2(bl_re[h*128 + b], bl_im[h*128 + b]);
            acc = cfma(s, bl, acc);
        }
        Clds[h][a] = acc;
    }
    __syncthreads();
    float2 tot;
    {
        float2 tp = make_float2(0,0);
        for (int q = 0; q < 4; ++q) tp = cfma(MtLds[1][h*4 + q], Clds[q][a], tp);
        float2 blv = make_float2(bl_re[h*128 + a], bl_im[h*128 + a]);
        tot = cfmac(blv, tp, make_float2(0,0));
    }
    for (int off = 32; off; off >>= 1) {
        tot.x += __shfl_down(tot.x, off, 64);
        tot.y += __shfl_down(tot.y, off, 64);
    }
    if ((tid & 63) == 0) fred[tid >> 6] = tot;
    __syncthreads();
    if (tid == 0) {
        float2 s = make_float2(0,0);
        for (int w = 0; w < 8; ++w) { s.x += fred[w].x; s.y += fred[w].y; }
        out[0] = s.x;
        if (out_size > 1) out[1] = s.y;
    }
}

// ---------------------------------------------------------------------------
extern "C" void kernel_launch(void* const* d_in, const int* in_sizes, int n_in,
                              void* d_out, int out_size, void* d_ws, size_t ws_size,
                              hipStream_t stream)
{
    const float* a_re  = (const float*)d_in[0];
    const float* a_im  = (const float*)d_in[1];
    const float* b0_re = (const float*)d_in[2];
    const float* b0_im = (const float*)d_in[3];
    const float* bm_re = (const float*)d_in[4];
    const float* bm_im = (const float*)d_in[5];
    const float* bl_re = (const float*)d_in[6];
    const float* bl_im = (const float*)d_in[7];
    const int*  tokens = (const int*)d_in[8];

    char* ws = (char*)d_ws;
    float2* S0   = (float2*)(ws + 196608);            // 131072 B
    float2* S1b  = (float2*)(ws + 327680);            // 131072 B
    unsigned int* cnt = (unsigned int*)(ws + 458752); // 2048 B

    zero_cnt<<<dim3(1), dim3(512), 0, stream>>>(cnt);

    float* outf = (float*)d_out;
    int osz = out_size;
    void* args[] = {
        (void*)&a_re, (void*)&a_im, (void*)&b0_re, (void*)&b0_im,
        (void*)&bm_re, (void*)&bm_im, (void*)&bl_re, (void*)&bl_im,
        (void*)&tokens,
        (void*)&S0, (void*)&S1b, (void*)&cnt, (void*)&outf, (void*)&osz
    };
    hipLaunchCooperativeKernel((const void*)scan_kernel, dim3(128), dim3(512),
                               args, 0, stream);
}

// Round 8
// 247.718 us; speedup vs baseline: 2.2116x; 1.0510x over previous
//
#include <hip/hip_runtime.h>
#include <hip/hip_bf16.h>

// ---------------------------------------------------------------------------
// MPS contraction, N=512 sites, D_PHY=4, D_BOND=128, VOC=1024.
// Faithful computation with EXACT all-zero early exit (state underflows to
// exact 0 after ~15 sites; site map is linear, so remaining sites stay 0).
// Round-8: wave-specialized prefetch. vmcnt retires FIFO per wave, so any
// cold load issued by a compute wave poisons that wave's later hot-load waits
// AND every __syncthreads vmcnt(0) drain. Fix: 576-thr wgs = 8 compute waves
// (mappings unchanged) + 1 prefetch wave owning ALL cold traffic (tile warm
// one site ahead, next site's C-operands gathered into LDS Bpre, M_{t+1}).
// Intra-site barriers are lgkm-only (raw s_barrier) so compute waves never
// drain vmcnt except at the site barrier. Warm lead t+1 makes the Bpre
// gather MALL-hit instead of cold-HBM.
// ---------------------------------------------------------------------------

__device__ __forceinline__ float2 cfma(float2 a, float2 b, float2 acc) {
    acc.x = fmaf(a.x, b.x, fmaf(-a.y, b.y, acc.x));
    acc.y = fmaf(a.x, b.y, fmaf( a.y, b.x, acc.y));
    return acc;
}
__device__ __forceinline__ float2 cfmac(float2 a, float2 b, float2 acc) {
    // acc + conj(a)*b
    acc.x = fmaf(a.x, b.x, fmaf( a.y, b.y, acc.x));
    acc.y = fmaf(a.x, b.y, fmaf(-a.y, b.x, acc.y));
    return acc;
}

// coherent (cache-bypassing) 8-byte load/store for the S exchange
__device__ __forceinline__ float2 ld_coh(const float2* p) {
    union { unsigned long long u; float2 f; } cv;
    cv.u = __hip_atomic_load((const unsigned long long*)p,
                             __ATOMIC_RELAXED, __HIP_MEMORY_SCOPE_AGENT);
    return cv.f;
}
__device__ __forceinline__ void st_coh(float2* p, float2 x) {
    union { unsigned long long u; float2 f; } cv;
    cv.f = x;
    __hip_atomic_store((unsigned long long*)p, cv.u,
                       __ATOMIC_RELAXED, __HIP_MEMORY_SCOPE_AGENT);
}

__device__ __forceinline__ double2 d2mul(double2 a, double2 b) {
    return make_double2(a.x*b.x - a.y*b.y, a.x*b.y + a.y*b.x);
}
__device__ __forceinline__ double2 d2conj(double2 a) { return make_double2(a.x, -a.y); }
__device__ __forceinline__ double2 d2add(double2 a, double2 b) {
    return make_double2(a.x + b.x, a.y + b.y);
}
__device__ __forceinline__ double2 d2sub(double2 a, double2 b) {
    return make_double2(a.x - b.x, a.y - b.y);
}

// LDS-only barrier: does NOT drain vmcnt (raw s_barrier). All LDS producers
// wait their own lgkmcnt first; sched_barrier pins codegen ordering.
__device__ __forceinline__ void lds_barrier() {
    asm volatile("s_waitcnt lgkmcnt(0)" ::: "memory");
    __builtin_amdgcn_s_barrier();
    __builtin_amdgcn_sched_barrier(0);
}

// batched block reduction over 9 waves (576 thr): n (<=4) double2 values
// in one sync round. Waves with no contribution pass zeros. Deterministic.
__device__ void redN(double2* v, int n, double2 (*redm)[4]) {
    for (int off = 32; off; off >>= 1) {
        for (int d = 0; d < n; ++d) {
            v[d].x += __shfl_down(v[d].x, off, 64);
            v[d].y += __shfl_down(v[d].y, off, 64);
        }
    }
    const int wid = threadIdx.x >> 6, lane = threadIdx.x & 63;
    __syncthreads();
    if (lane == 0)
        for (int d = 0; d < n; ++d) redm[wid][d] = v[d];
    __syncthreads();
    for (int d = 0; d < n; ++d) {
        double2 s = make_double2(0.0, 0.0);
        for (int w = 0; w < 9; ++w) { s.x += redm[w][d].x; s.y += redm[w][d].y; }
        v[d] = s;
    }
}

// M entry m=(j,k) for token v: Y = A_v * W (4x4), M[j,k] = sum_i conj(Y[i,j])Y[i,k]
__device__ __forceinline__ float2 m_entry(const float* __restrict__ a_re,
                                          const float* __restrict__ a_im,
                                          int v, int m, const float2* Wl)
{
    const int j = m >> 2, k = m & 3;
    float2 Arow[4][4];
    #pragma unroll
    for (int i = 0; i < 4; ++i) {
        float4 re = *(const float4*)(a_re + v*16 + i*4);
        float4 im = *(const float4*)(a_im + v*16 + i*4);
        Arow[i][0] = make_float2(re.x, im.x);
        Arow[i][1] = make_float2(re.y, im.y);
        Arow[i][2] = make_float2(re.z, im.z);
        Arow[i][3] = make_float2(re.w, im.w);
    }
    float2 acc = make_float2(0.f, 0.f);
    #pragma unroll
    for (int i = 0; i < 4; ++i) {
        float2 yj = make_float2(0.f, 0.f), yk = yj;
        #pragma unroll
        for (int q = 0; q < 4; ++q) {
            yj = cfma(Arow[i][q], Wl[q*4 + j], yj);
            yk = cfma(Arow[i][q], Wl[q*4 + k], yk);
        }
        acc = cfmac(yj, yk, acc);
    }
    return acc;
}

// 16 batched cache-bypassing S loads (one asm block: issue all, wait once).
// Per-wave vmcnt is clean (no cold loads on compute waves), so vmcnt(0)
// waits exactly these 16.
#define LD16_FMA(BB0)                                                         \
  {                                                                           \
    const float2* _p0 = Sread + (BB0) * 128 + a;                              \
    const float2* _p1 = _p0 + 512;                                            \
    const float2* _p2 = _p0 + 1024;                                           \
    const float2* _p3 = _p0 + 1536;                                           \
    float2 t0,t1,t2,t3,t4,t5,t6,t7,t8,t9,t10,t11,t12,t13,t14,t15;             \
    asm volatile(                                                             \
      "global_load_dwordx2 %0, %16, off sc0 sc1\n\t"                          \
      "global_load_dwordx2 %1, %16, off offset:1024 sc0 sc1\n\t"              \
      "global_load_dwordx2 %2, %16, off offset:2048 sc0 sc1\n\t"              \
      "global_load_dwordx2 %3, %16, off offset:3072 sc0 sc1\n\t"              \
      "global_load_dwordx2 %4, %17, off sc0 sc1\n\t"                          \
      "global_load_dwordx2 %5, %17, off offset:1024 sc0 sc1\n\t"              \
      "global_load_dwordx2 %6, %17, off offset:2048 sc0 sc1\n\t"              \
      "global_load_dwordx2 %7, %17, off offset:3072 sc0 sc1\n\t"              \
      "global_load_dwordx2 %8, %18, off sc0 sc1\n\t"                          \
      "global_load_dwordx2 %9, %18, off offset:1024 sc0 sc1\n\t"              \
      "global_load_dwordx2 %10, %18, off offset:2048 sc0 sc1\n\t"             \
      "global_load_dwordx2 %11, %18, off offset:3072 sc0 sc1\n\t"             \
      "global_load_dwordx2 %12, %19, off sc0 sc1\n\t"                         \
      "global_load_dwordx2 %13, %19, off offset:1024 sc0 sc1\n\t"             \
      "global_load_dwordx2 %14, %19, off offset:2048 sc0 sc1\n\t"             \
      "global_load_dwordx2 %15, %19, off offset:3072 sc0 sc1\n\t"             \
      "s_waitcnt vmcnt(0)"                                                    \
      : "=&v"(t0), "=&v"(t1), "=&v"(t2), "=&v"(t3),                           \
        "=&v"(t4), "=&v"(t5), "=&v"(t6), "=&v"(t7),                           \
        "=&v"(t8), "=&v"(t9), "=&v"(t10), "=&v"(t11),                         \
        "=&v"(t12), "=&v"(t13), "=&v"(t14), "=&v"(t15)                        \
      : "v"(_p0), "v"(_p1), "v"(_p2), "v"(_p3));                              \
    float2 tt[16] = {t0,t1,t2,t3,t4,t5,t6,t7,t8,t9,t10,t11,t12,t13,t14,t15};  \
    _Pragma("unroll")                                                         \
    for (int jj = 0; jj < 16; ++jj) {                                         \
        float2 sv = tt[jj];                                                   \
        u0 = cfma(sv, Clds[0][(BB0) + jj], u0);                               \
        u1 = cfma(sv, Clds[1][(BB0) + jj], u1);                               \
        u2 = cfma(sv, Clds[2][(BB0) + jj], u2);                               \
        u3 = cfma(sv, Clds[3][(BB0) + jj], u3);                               \
    }                                                                         \
  }

// ---------------------------------------------------------------------------
// Tiny init: zero the 512 barrier words (fresh every replay).
// ---------------------------------------------------------------------------
__global__ __launch_bounds__(512) void zero_cnt(unsigned int* __restrict__ cnt)
{
    cnt[threadIdx.x] = 0u;
}

// ---------------------------------------------------------------------------
// Flat fused grid barrier + liveness, fence-free (round-3 design).
// S stores are write-through (sc0+sc1); __syncthreads() drains vmcnt for
// every wave, so by the time tid 0 adds, this wg's S is globally visible.
// Count field == 128 => word final => liveness bits consistent & uniform.
// ---------------------------------------------------------------------------
#define NWG 128u
__device__ __forceinline__ bool site_barrier(unsigned int* addr,
                                             unsigned* nzw, int* live_lds, int tid)
{
    __syncthreads();                 // drains vmcnt(0) for all waves
    if (tid == 0) {
        unsigned add = 1u | ((nzw[0] | nzw[1]) ? 0x10000u : 0u);
        __hip_atomic_fetch_add(addr, add, __ATOMIC_RELAXED, __HIP_MEMORY_SCOPE_AGENT);
        unsigned v;
        for (;;) {
            v = __hip_atomic_load(addr, __ATOMIC_RELAXED, __HIP_MEMORY_SCOPE_AGENT);
            if ((v & 0xffffu) >= NWG) break;
            __builtin_amdgcn_s_sleep(1);
        }
        *live_lds = (int)(v >> 16);
    }
    __syncthreads();
    return *live_lds != 0;
}

// ---------------------------------------------------------------------------
// The one cooperative kernel. 128 wgs x 576 threads (8 compute waves + 1
// prefetch wave); wg owns output column c (XCD-grouped mapping).
// ---------------------------------------------------------------------------
__global__ __launch_bounds__(576) void scan_kernel(
    const float* __restrict__ a_re,  const float* __restrict__ a_im,
    const float* __restrict__ b0_re, const float* __restrict__ b0_im,
    const float* __restrict__ bm_re, const float* __restrict__ bm_im,
    const float* __restrict__ bl_re, const float* __restrict__ bl_im,
    const int*  __restrict__ tokens,
    float2* SbufA, float2* SbufB,
    unsigned int* cnt, float* out, int out_size)
{
    const int tid = threadIdx.x;
    const int bid = blockIdx.x;
    const int c = ((bid & 7) << 4) | (bid >> 3);   // same-XCD wgs -> adjacent c

    __shared__ float2 Clds[4][128];
    __shared__ float2 Upart[4][512];
    __shared__ float2 U[512];
    __shared__ float2 red4[4][128];
    __shared__ float2 fred[16];
    __shared__ double2 redm[9][4];
    __shared__ float2 Wlds[16];
    __shared__ float2 MtLds[2][16];
    __shared__ float2 Bpre[2][4][128];   // C-step operands, double-buffered
    __shared__ unsigned nzw[2];
    __shared__ int live_lds;

    const int a = tid & 127;
    const int h = tid >> 7;          // quarter id 0..3 for compute threads

    float2* Sread = SbufA;
    float2* Swrite = SbufB;
    bool dead = false;
    float warmacc = 0.f;

    // ---- warm tiles 0 and 1 (compute threads; prologue timing non-critical)
    if (tid < 512) {
        const int g  = (c << 9) | tid;
        const int g2 = (g + 32768) & 65535;
        warmacc += bm_re[g] + bm_im[g] + bm_re[g2] + bm_im[g2];
        warmacc += bm_re[65536 + g] + bm_im[65536 + g]
                 + bm_re[65536 + g2] + bm_im[65536 + g2];
    }

    // =======================================================================
    // Prologue A: Gram G = A^H A (4096x4), redundant per wg, deterministic.
    // =======================================================================
    double2 gp[10];
    #pragma unroll
    for (int e = 0; e < 10; ++e) gp[e] = make_double2(0.0, 0.0);
    if (tid < 512) {
        for (int rr = 0; rr < 8; ++rr) {
            const int r = tid * 8 + rr;
            float4 fre = *(const float4*)(a_re + r*4);
            float4 fim = *(const float4*)(a_im + r*4);
            double r0 = fre.x, r1 = fre.y, r2 = fre.z, r3 = fre.w;
            double i0 = fim.x, i1 = fim.y, i2 = fim.z, i3 = fim.w;
#define GACC(e, rj, ij, rk, ik) \
            gp[e].x += rj*rk + ij*ik; gp[e].y += rj*ik - ij*rk;
            GACC(0, r0, i0, r0, i0)  GACC(1, r0, i0, r1, i1)
            GACC(2, r0, i0, r2, i2)  GACC(3, r0, i0, r3, i3)
            GACC(4, r1, i1, r1, i1)  GACC(5, r1, i1, r2, i2)
            GACC(6, r1, i1, r3, i3)  GACC(7, r2, i2, r2, i2)
            GACC(8, r2, i2, r3, i3)  GACC(9, r3, i3, r3, i3)
#undef GACC
        }
    }
    redN(gp + 0, 4, redm);
    redN(gp + 4, 4, redm);
    redN(gp + 8, 2, redm);

    double2 G4[4][4];
    G4[0][0]=gp[0]; G4[0][1]=gp[1]; G4[0][2]=gp[2]; G4[0][3]=gp[3];
    G4[1][1]=gp[4]; G4[1][2]=gp[5]; G4[1][3]=gp[6];
    G4[2][2]=gp[7]; G4[2][3]=gp[8]; G4[3][3]=gp[9];
    G4[1][0]=d2conj(gp[1]); G4[2][0]=d2conj(gp[2]); G4[3][0]=d2conj(gp[3]);
    G4[2][1]=d2conj(gp[5]); G4[3][1]=d2conj(gp[6]); G4[3][2]=d2conj(gp[8]);
    G4[0][0].y=0.0; G4[1][1].y=0.0; G4[2][2].y=0.0; G4[3][3].y=0.0;

    // =======================================================================
    // Prologue B: LAPACK diag-sign recurrence, Cholesky, W = R^-1 D.
    // Redundant per thread (uniform); tid 0 publishes W.
    // =======================================================================
    {
        double2 T[4][4];
        #pragma unroll
        for (int i = 0; i < 4; ++i)
            #pragma unroll
            for (int j = 0; j < 4; ++j)
                T[i][j] = make_double2((double)a_re[i*4+j], (double)a_im[i*4+j]);

        double dsgn[4];
        #pragma unroll
        for (int k = 0; k < 4; ++k) {
            double ssum = 0.0;
            #pragma unroll
            for (int i = 0; i < 4; ++i)
                if (i <= k) ssum += T[i][k].x*T[i][k].x + T[i][k].y*T[i][k].y;
            double xn = G4[k][k].x - ssum; if (xn < 0.0) xn = 0.0;
            double ar = T[k][k].x, ai = T[k][k].y;
            double nrm = sqrt(ar*ar + ai*ai + xn);
            double beta = (ar >= 0.0) ? -nrm : nrm;        // clarfg sign rule
            dsgn[k] = (beta >= 0.0) ? 1.0 : -1.0;
            double2 tau = make_double2((beta - ar)/beta, -ai/beta);
            double dr = ar - beta, di = ai;
            double dd = dr*dr + di*di;
            double2 s = make_double2(dr/dd, -di/dd);       // 1/(alpha-beta)
            double2 w[4];
            #pragma unroll
            for (int j = 0; j < 4; ++j) if (j > k) {
                double2 acc = G4[k][j];
                #pragma unroll
                for (int i = 0; i < 4; ++i)
                    if (i <= k) acc = d2sub(acc, d2mul(d2conj(T[i][k]), T[i][j]));
                w[j] = d2add(T[k][j], d2mul(d2conj(s), acc));
            }
            #pragma unroll
            for (int j = 0; j < 4; ++j) if (j > k) {
                double2 tw = d2mul(tau, w[j]);
                T[k][j] = d2sub(T[k][j], tw);
                #pragma unroll
                for (int i = 0; i < 4; ++i)
                    if (i > k) T[i][j] = d2sub(T[i][j], d2mul(tw, d2mul(s, T[i][k])));
            }
            T[k][k] = make_double2(beta, 0.0);
            #pragma unroll
            for (int i = 0; i < 4; ++i)
                if (i > k) T[i][k] = make_double2(0.0, 0.0);
        }

        double2 R[4][4];
        #pragma unroll
        for (int k = 0; k < 4; ++k) {
            double dk = G4[k][k].x;
            #pragma unroll
            for (int i = 0; i < 4; ++i)
                if (i < k) dk -= R[i][k].x*R[i][k].x + R[i][k].y*R[i][k].y;
            if (dk < 1e-30) dk = 1e-30;
            double rkk = sqrt(dk);
            R[k][k] = make_double2(rkk, 0.0);
            #pragma unroll
            for (int j = 0; j < 4; ++j) if (j > k) {
                double2 acc = G4[k][j];
                #pragma unroll
                for (int i = 0; i < 4; ++i)
                    if (i < k) acc = d2sub(acc, d2mul(d2conj(R[i][k]), R[i][j]));
                R[k][j] = make_double2(acc.x/rkk, acc.y/rkk);
            }
        }
        double2 X[4][4];
        #pragma unroll
        for (int j = 0; j < 4; ++j) {
            #pragma unroll
            for (int i = 0; i < 4; ++i) X[i][j] = make_double2(0.0, 0.0);
            X[j][j] = make_double2(1.0 / R[j][j].x, 0.0);
            #pragma unroll
            for (int ii = 0; ii < 3; ++ii) {
                const int i = j - 1 - ii;
                if (i >= 0) {
                    double2 acc = make_double2(0.0, 0.0);
                    #pragma unroll
                    for (int m2 = 0; m2 < 4; ++m2)
                        if (m2 > i && m2 <= j) acc = d2add(acc, d2mul(R[i][m2], X[m2][j]));
                    X[i][j] = make_double2(-acc.x / R[i][i].x, -acc.y / R[i][i].x);
                }
            }
        }
        if (tid == 0) {
            #pragma unroll
            for (int q = 0; q < 4; ++q)
                #pragma unroll
                for (int j = 0; j < 4; ++j)
                    Wlds[q*4 + j] = make_float2((float)(X[q][j].x * dsgn[j]),
                                                (float)(X[q][j].y * dsgn[j]));
        }
    }
    __syncthreads();

    // ---- M_0, M_1 and Bpre[1] (site 1 C-operands, tile 0)
    if (tid < 32) {
        const int which = tid >> 4, m = tid & 15;
        MtLds[which][m] = m_entry(a_re, a_im, tokens[which], m, Wlds);
    }
    if (tid < 512) {
        Bpre[1][h][a] = make_float2(bm_re[(h*128 + a)*128 + c],
                                    bm_im[(h*128 + a)*128 + c]);
    }
    __syncthreads();

    // ---- site 0: threads tid<128 compute column c of S0 (transposed store)
    if (tid < 128) {
        const int r = a;
        float2 brr[4], bcc[4];
        for (int p = 0; p < 4; ++p) {
            brr[p] = make_float2(b0_re[p*128 + r], b0_im[p*128 + r]);
            bcc[p] = make_float2(b0_re[p*128 + c], b0_im[p*128 + c]);
        }
        float2 acc = make_float2(0.f, 0.f);
        for (int p = 0; p < 4; ++p) {
            float2 tp = make_float2(0.f, 0.f);
            for (int q = 0; q < 4; ++q) tp = cfma(MtLds[0][p*4 + q], bcc[q], tp);
            acc = cfmac(brr[p], tp, acc);
        }
        st_coh(&SbufA[c*128 + r], acc);
        int nz = (acc.x != 0.f) || (acc.y != 0.f);
        unsigned long long m = __ballot(nz);
        if ((tid & 63) == 0) nzw[tid >> 6] = (m != 0ULL) ? 1u : 0u;
    }

    if (!site_barrier(&cnt[0], nzw, &live_lds, tid)) dead = true;

    if (!dead) {
        for (int t = 1; t <= 510; ++t) {
            const int cur = t & 1, nxt = cur ^ 1;
            const float* br = bm_re + (size_t)(t - 1) * 65536;
            const float* bi = bm_im + (size_t)(t - 1) * 65536;

            // ================= prefetch wave (tid >= 512) =================
            if (tid >= 512) {
                const int j = tid - 512;               // 0..63
                // (a) warm tile t+1 (contiguous 4 KB/wg split over 64 thr)
                float4 wa = make_float4(0,0,0,0), wb = wa, wc = wa, wd = wa;
                if (t < 509) {
                    const float* wr = bm_re + (size_t)(t+1)*65536 + c*512 + j*8;
                    const float* wi = bm_im + (size_t)(t+1)*65536 + c*512 + j*8;
                    wa = *(const float4*)wr;  wb = *(const float4*)(wr + 4);
                    wc = *(const float4*)wi;  wd = *(const float4*)(wi + 4);
                }
                // (b) Bpre gather for site t+1 from tile t (MALL-warm)
                float2 bp[8];
                if (t < 510) {
                    const float* br2 = bm_re + (size_t)t * 65536;
                    const float* bi2 = bm_im + (size_t)t * 65536;
                    #pragma unroll
                    for (int e = 0; e < 8; ++e) {
                        const int idx = j*8 + e, q = idx >> 7, a2 = idx & 127;
                        bp[e] = make_float2(br2[(q*128 + a2)*128 + c],
                                            bi2[(q*128 + a2)*128 + c]);
                    }
                }
                // (c) M_{t+1} (threads 0-15)
                float2 macc = make_float2(0.f, 0.f);
                if (j < 16) macc = m_entry(a_re, a_im, tokens[t+1], j, Wlds);
                // commit to LDS (compiler waits this wave's own vmcnt)
                if (t < 510) {
                    #pragma unroll
                    for (int e = 0; e < 8; ++e) {
                        const int idx = j*8 + e, q = idx >> 7, a2 = idx & 127;
                        Bpre[nxt][q][a2] = bp[e];
                    }
                }
                if (j < 16) MtLds[nxt][j] = macc;
                warmacc += wa.x+wa.y+wa.z+wa.w + wb.x+wb.y+wb.z+wb.w
                         + wc.x+wc.y+wc.z+wc.w + wd.x+wd.y+wd.z+wd.w;
            }

            // ================= compute waves (tid < 512) ==================
            // ---- C[p=h][a] from LDS Bpre + LDS M row (no global loads)
            if (tid < 512) {
                float2 acc = make_float2(0.f, 0.f);
                #pragma unroll
                for (int q = 0; q < 4; ++q)
                    acc = cfma(MtLds[cur][h*4 + q], Bpre[cur][q][a], acc);
                Clds[h][a] = acc;
            }
            lds_barrier();

            // ---- U[p][a] = sum_b S[a,b] C[p][b]; quarter-split b
            if (tid < 512) {
                float2 u0 = make_float2(0,0), u1 = u0, u2 = u0, u3 = u0;
                LD16_FMA(h * 32)
                LD16_FMA(h * 32 + 16)
                Upart[h][0*128 + a] = u0;
                Upart[h][1*128 + a] = u1;
                Upart[h][2*128 + a] = u2;
                Upart[h][3*128 + a] = u3;
            }
            lds_barrier();
            if (tid < 512) {
                float2 x0 = Upart[0][tid], x1 = Upart[1][tid];
                float2 x2 = Upart[2][tid], x3 = Upart[3][tid];
                U[tid] = make_float2(x0.x + x1.x + x2.x + x3.x,
                                     x0.y + x1.y + x2.y + x3.y);
            }
            lds_barrier();

            // ---- S'[r,c] partial: quarter-split pa (tile warmed 2 sites ago)
            if (tid < 512) {
                const int r = a;
                float2 o0 = make_float2(0,0), o1 = o0;
                #pragma unroll 4
                for (int pa = h * 128; pa < h * 128 + 128; pa += 2) {
                    float2 b1 = make_float2(br[pa*128 + r],     bi[pa*128 + r]);
                    float2 b2 = make_float2(br[(pa+1)*128 + r], bi[(pa+1)*128 + r]);
                    o0 = cfmac(b1, U[pa],     o0);
                    o1 = cfmac(b2, U[pa + 1], o1);
                }
                o0.x += o1.x; o0.y += o1.y;
                red4[h][r] = o0;
            }
            lds_barrier();
            if (tid < 128) {
                const int r = a;
                float2 fin = make_float2(
                    red4[0][r].x + red4[1][r].x + red4[2][r].x + red4[3][r].x,
                    red4[0][r].y + red4[1][r].y + red4[2][r].y + red4[3][r].y);
                st_coh(&Swrite[c * 128 + r], fin);          // write-through
                int nz = (fin.x != 0.f) || (fin.y != 0.f);
                unsigned long long m = __ballot(nz);
                if ((tid & 63) == 0) nzw[tid >> 6] = (m != 0ULL) ? 1u : 0u;
            }

            if (!site_barrier(&cnt[t], nzw, &live_lds, tid)) { dead = true; break; }
            float2* tmp = Sread; Sread = Swrite; Swrite = tmp;
        }
    }

    if (out_size < 0) out[2] = warmacc;        // never true: keeps warm loads

    if (dead) {
        if (bid == 0 && tid == 0) {
            out[0] = 0.f;
            if (out_size > 1) out[1] = 0.f;
        }
        return;
    }
    if (bid != 0) return;

    // ---- final site: Bl (4,128,1), M_511 = MtLds[1]; Sread = S(510) transposed
    if (tid < 512) {   // t1[q=h][a] = sum_b S[a,b] * Bl[q,b]
        float2 acc = make_float2(0,0);
        for (int b = 0; b < 128; ++b) {
            float2 s = ld_coh(&Sread[b * 128 + a]);
            float2 bl = make_float2(bl_re[h*128 + b], bl_im[h*128 + b]);
            acc = cfma(s, bl, acc);
        }
        Clds[h][a] = acc;
    }
    __syncthreads();
    float2 tot = make_float2(0,0);
    if (tid < 512) {
        float2 tp = make_float2(0,0);
        for (int q = 0; q < 4; ++q) tp = cfma(MtLds[1][h*4 + q], Clds[q][a], tp);
        float2 blv = make_float2(bl_re[h*128 + a], bl_im[h*128 + a]);
        tot = cfmac(blv, tp, make_float2(0,0));
    }
    for (int off = 32; off; off >>= 1) {
        tot.x += __shfl_down(tot.x, off, 64);
        tot.y += __shfl_down(tot.y, off, 64);
    }
    if ((tid & 63) == 0) fred[tid >> 6] = tot;
    __syncthreads();
    if (tid == 0) {
        float2 s = make_float2(0,0);
        for (int w = 0; w < 9; ++w) { s.x += fred[w].x; s.y += fred[w].y; }
        out[0] = s.x;
        if (out_size > 1) out[1] = s.y;
    }
}

// ---------------------------------------------------------------------------
extern "C" void kernel_launch(void* const* d_in, const int* in_sizes, int n_in,
                              void* d_out, int out_size, void* d_ws, size_t ws_size,
                              hipStream_t stream)
{
    const float* a_re  = (const float*)d_in[0];
    const float* a_im  = (const float*)d_in[1];
    const float* b0_re = (const float*)d_in[2];
    const float* b0_im = (const float*)d_in[3];
    const float* bm_re = (const float*)d_in[4];
    const float* bm_im = (const float*)d_in[5];
    const float* bl_re = (const float*)d_in[6];
    const float* bl_im = (const float*)d_in[7];
    const int*  tokens = (const int*)d_in[8];

    char* ws = (char*)d_ws;
    float2* S0   = (float2*)(ws + 196608);            // 131072 B
    float2* S1b  = (float2*)(ws + 327680);            // 131072 B
    unsigned int* cnt = (unsigned int*)(ws + 458752); // 2048 B

    zero_cnt<<<dim3(1), dim3(512), 0, stream>>>(cnt);

    float* outf = (float*)d_out;
    int osz = out_size;
    void* args[] = {
        (void*)&a_re, (void*)&a_im, (void*)&b0_re, (void*)&b0_im,
        (void*)&bm_re, (void*)&bm_im, (void*)&bl_re, (void*)&bl_im,
        (void*)&tokens,
        (void*)&S0, (void*)&S1b, (void*)&cnt, (void*)&outf, (void*)&osz
    };
    hipLaunchCooperativeKernel((const void*)scan_kernel, dim3(128), dim3(576),
                               args, 0, stream);
}